// Round 6
// baseline (46703.137 us; speedup 1.0000x reference)
//
#include <hip/hip_runtime.h>
#include <hip/hip_bf16.h>
#include <math.h>

// RSSM scan — numpy-realization f32 compute, round 6 cell:
// GEMM: OpenBLAS sgemm replica (K blocked Q=384, single-acc k-ascending fmaf,
//       panels folded ((p0+p1)+p2)).  Reductions: numpy pairwise replica.
// Transcendentals: correctly-rounded f32 via f64 (<=0.5 ulp of numpy SIMD).
// Elementwise: *_rn chains in numpy op order. Outputs f32.
// B=256, T=64, HID=GRU=EMBED=1024, SD=SC=32, ADIM=6.

struct GArg {
  const float* A0; int lda0;        // K-segment 0
  const float* A1; int lda1;        // K-segment 1 (k >= kSplit)
  int kSplit;
  const float* W; int ldw;          // weights (N x K) row-major f32
  float* C; int N; int K;
};

__device__ __forceinline__ float exp_cr(float x)  { return (float)exp((double)x); }
__device__ __forceinline__ float log_cr(float x)  { return (float)log((double)x); }
__device__ __forceinline__ float tanh_cr(float x) { return (float)tanh((double)x); }

__device__ __forceinline__ float sigmoid_cr(float x) {
  float e = exp_cr(-x);
  float d = __fadd_rn(1.0f, e);
  return __fdiv_rn(1.0f, d);
}

// C[m,n] = sum_k A[m,k]*W[n,k]; tile 64x64, BK=16; per-element fmaf chains of
// 384 k (24 tiles), chain subtotals combined by plain adds (OpenBLAS GEMM_Q).
__global__ __launch_bounds__(256) void gemm_k(GArg g0, GArg g1) {
  GArg G = (blockIdx.z == 0) ? g0 : g1;
  int n0 = blockIdx.x * 64;
  if (n0 >= G.N) return;
  int m0 = blockIdx.y * 64;

  __shared__ float As[16][64];   // [k][m]
  __shared__ float Bs[16][64];   // [k][n]

  int tid = threadIdx.x;
  int tx = tid & 15, ty = tid >> 4;
  int sm = tid >> 2, skb = (tid & 3) * 4;

  float acc[4][4], sum[4][4];
  #pragma unroll
  for (int j = 0; j < 4; ++j)
    #pragma unroll
    for (int i = 0; i < 4; ++i) { acc[j][i] = 0.0f; sum[j][i] = 0.0f; }

  int nt = (G.K + 15) >> 4;
  for (int kt = 0; kt < nt; ++kt) {
    if (kt > 0 && (kt % 24) == 0) {        // 384-k block boundary: fold chain
      #pragma unroll
      for (int j = 0; j < 4; ++j)
        #pragma unroll
        for (int i = 0; i < 4; ++i) {
          sum[j][i] = __fadd_rn(sum[j][i], acc[j][i]);
          acc[j][i] = 0.0f;
        }
    }
    int kb = kt * 16;
    #pragma unroll
    for (int i = 0; i < 4; ++i) {
      int k = kb + skb + i;
      float av = 0.0f, wv = 0.0f;
      if (k < G.K) {
        if (k < G.kSplit) av = G.A0[(size_t)(m0 + sm) * G.lda0 + k];
        else              av = G.A1[(size_t)(m0 + sm) * G.lda1 + (k - G.kSplit)];
        wv = G.W[(size_t)(n0 + sm) * G.ldw + k];
      }
      As[skb + i][sm] = av;
      Bs[skb + i][sm] = wv;
    }
    __syncthreads();
    #pragma unroll
    for (int kk = 0; kk < 16; ++kk) {
      float a[4], b[4];
      #pragma unroll
      for (int j = 0; j < 4; ++j) a[j] = As[kk][ty + 16 * j];
      #pragma unroll
      for (int i = 0; i < 4; ++i) b[i] = Bs[kk][tx + 16 * i];
      #pragma unroll
      for (int j = 0; j < 4; ++j)
        #pragma unroll
        for (int i = 0; i < 4; ++i)
          acc[j][i] = fmaf(a[j], b[i], acc[j][i]);   // k-sequential chain
    }
    __syncthreads();
  }

  #pragma unroll
  for (int j = 0; j < 4; ++j) {
    int m = m0 + ty + 16 * j;
    #pragma unroll
    for (int i = 0; i < 4; ++i)
      G.C[(size_t)m * G.N + (n0 + tx + 16 * i)] = __fadd_rn(sum[j][i], acc[j][i]);
  }
}

// numpy pairwise sum over 1024: lane kb=l>>3,j=l&7 owns a[kb*128+8i+j] i=0..15
// sequential; combine xor 1,2,4 (within 128-block tree), xor 8,16,32 (blocks).
__device__ __forceinline__ float pairwise1024(const float* v /*16 per lane*/) {
  float r = v[0];
  #pragma unroll
  for (int i = 1; i < 16; ++i) r = __fadd_rn(r, v[i]);
  r = __fadd_rn(r, __shfl_xor(r, 1));
  r = __fadd_rn(r, __shfl_xor(r, 2));
  r = __fadd_rn(r, __shfl_xor(r, 4));
  r = __fadd_rn(r, __shfl_xor(r, 8));
  r = __fadd_rn(r, __shfl_xor(r, 16));
  r = __fadd_rn(r, __shfl_xor(r, 32));
  return r;
}

// ---- LN + SiLU rows of 1024 (bias added into LN input); wave per row ----
__global__ __launch_bounds__(256) void lnsilu_k(
  const float* Y0, const float* bias0, const float* g0, const float* be0, float* O0,
  const float* Y1, const float* bias1, const float* g1, const float* be1, float* O1)
{
  int pair = blockIdx.y;
  const float* Y = pair ? Y1 : Y0;
  const float* bias = pair ? bias1 : bias0;
  const float* gg   = pair ? g1 : g0;
  const float* be   = pair ? be1 : be0;
  float* O = pair ? O1 : O0;

  int tid = threadIdx.x;
  int row = blockIdx.x * 4 + (tid >> 6);
  int lane = tid & 63, kb = lane >> 3, j = lane & 7;

  float xv[16];
  #pragma unroll
  for (int i = 0; i < 16; ++i) {
    int n = kb * 128 + 8 * i + j;
    xv[i] = __fadd_rn(Y[(size_t)row * 1024 + n], bias[n]);
  }
  float mean = __fmul_rn(pairwise1024(xv), 0.0009765625f);
  float d[16], sq[16];
  #pragma unroll
  for (int i = 0; i < 16; ++i) { d[i] = __fsub_rn(xv[i], mean); sq[i] = __fmul_rn(d[i], d[i]); }
  float var = __fmul_rn(pairwise1024(sq), 0.0009765625f);
  float s = __fsqrt_rn(__fadd_rn(var, (float)1e-5));
  float rstd = __fdiv_rn(1.0f, s);
  #pragma unroll
  for (int i = 0; i < 16; ++i) {
    int n = kb * 128 + 8 * i + j;
    float t = __fmul_rn(__fmul_rn(d[i], rstd), gg[n]);
    t = __fadd_rn(t, be[n]);
    O[(size_t)row * 1024 + n] = __fmul_rn(t, sigmoid_cr(t));   // silu = x*sigmoid
  }
}

// ---- GRU combine + LN; wave per row; writes carry H and hs (f32) ----
__global__ __launch_bounds__(256) void gru_k(
  const float* GX, const float* GH, float* H,
  const float* b_ih, const float* b_hh, const float* g_gn, const float* b_gn,
  float* out, int t)
{
  int tid = threadIdx.x;
  int row = blockIdx.x * 4 + (tid >> 6);
  int lane = tid & 63, kb = lane >> 3, j = lane & 7;

  float hv[16];
  #pragma unroll
  for (int i = 0; i < 16; ++i) {
    int n = kb * 128 + 8 * i + j;
    size_t i0 = (size_t)row * 3072 + n;
    float xr = __fadd_rn(GX[i0],        b_ih[n]);
    float xu = __fadd_rn(GX[i0 + 1024], b_ih[n + 1024]);
    float xn = __fadd_rn(GX[i0 + 2048], b_ih[n + 2048]);
    float hr = __fadd_rn(GH[i0],        b_hh[n]);
    float hu = __fadd_rn(GH[i0 + 1024], b_hh[n + 1024]);
    float hn = __fadd_rn(GH[i0 + 2048], b_hh[n + 2048]);
    float r = sigmoid_cr(__fadd_rn(xr, hr));
    float u = sigmoid_cr(__fadd_rn(xu, hu));
    float nn = tanh_cr(__fadd_rn(xn, __fmul_rn(r, hn)));
    float h2 = __fadd_rn(__fmul_rn(__fsub_rn(1.0f, u), nn),
                         __fmul_rn(u, H[(size_t)row * 1024 + n]));
    hv[i] = h2;
  }
  float mean = __fmul_rn(pairwise1024(hv), 0.0009765625f);
  float d[16], sq[16];
  #pragma unroll
  for (int i = 0; i < 16; ++i) { d[i] = __fsub_rn(hv[i], mean); sq[i] = __fmul_rn(d[i], d[i]); }
  float var = __fmul_rn(pairwise1024(sq), 0.0009765625f);
  float s = __fsqrt_rn(__fadd_rn(var, (float)1e-5));
  float rstd = __fdiv_rn(1.0f, s);
  #pragma unroll
  for (int i = 0; i < 16; ++i) {
    int n = kb * 128 + 8 * i + j;
    float h3 = __fadd_rn(__fmul_rn(__fmul_rn(d[i], rstd), g_gn[n]), b_gn[n]);
    H[(size_t)row * 1024 + n] = h3;
    out[((size_t)row * 64 + t) * 1024 + n] = h3;
  }
}

// ---- softmax+unimix (+gumbel argmax posterior); pp/qp/zs, z-carry ----
__global__ __launch_bounds__(256) void sample_k(
  const float* Yp, const float* Yq, const float* bp2, const float* bq2,
  const float* u_post, const float* actions, float* XZ,
  float* out, int t)
{
  const size_t NOUT = 16777216ull;
  int pair = blockIdx.y, b = blockIdx.x, tid = threadIdx.x;
  int d = tid >> 3, lane = tid & 7;           // 32 dists x 8 lanes, 4 cats/lane
  const float* Y = pair ? Yq : Yp;
  const float* bias = pair ? bq2 : bp2;
  const float C0 = (float)(1.0 - 0.01);
  const float C1 = (float)(0.01 / 32.0);

  float lg[4];
  #pragma unroll
  for (int i = 0; i < 4; ++i) {
    int col = d * 32 + lane + 8 * i;          // c = lane + 8i
    lg[i] = __fadd_rn(Y[(size_t)b * 1024 + col], bias[col]);
  }
  float mx = fmaxf(fmaxf(lg[0], lg[1]), fmaxf(lg[2], lg[3]));
  for (int off = 4; off; off >>= 1) mx = fmaxf(mx, __shfl_xor(mx, off, 8));

  float e[4];
  #pragma unroll
  for (int i = 0; i < 4; ++i) e[i] = exp_cr(__fsub_rn(lg[i], mx));
  // numpy pairwise n=32: lane j sums a[j],a[8+j],a[16+j],a[24+j] seq; tree 1,2,4
  float ssum = e[0];
  ssum = __fadd_rn(ssum, e[1]);
  ssum = __fadd_rn(ssum, e[2]);
  ssum = __fadd_rn(ssum, e[3]);
  ssum = __fadd_rn(ssum, __shfl_xor(ssum, 1, 8));
  ssum = __fadd_rn(ssum, __shfl_xor(ssum, 2, 8));
  ssum = __fadd_rn(ssum, __shfl_xor(ssum, 4, 8));

  float p[4];
  #pragma unroll
  for (int i = 0; i < 4; ++i) {
    float pr = __fdiv_rn(e[i], ssum);
    p[i] = __fadd_rn(__fmul_rn(C0, pr), C1);  // (1-unimix)*probs + unimix/32
  }

  size_t ob = ((size_t)b * 64 + t) * 1024;
  if (!pair) {
    #pragma unroll
    for (int i = 0; i < 4; ++i)
      out[2 * NOUT + ob + (d * 32 + lane + 8 * i)] = p[i];
  } else {
    float bv = -3.4e38f; int bc = 33;
    #pragma unroll
    for (int i = 0; i < 4; ++i) {
      int c = lane + 8 * i, col = d * 32 + c;
      out[3 * NOUT + ob + col] = p[i];
      // gumbel = -log(-log(u)) as f32 op chain, CR logs
      float uu = u_post[((size_t)t * 256 + b) * 1024 + col];
      float l1 = log_cr(uu);
      float v1 = -l1;
      float l2 = log_cr(v1);
      float gu = -l2;
      float lp = log_cr(p[i]);
      float val = __fadd_rn(lp, gu);
      if (val > bv) { bv = val; bc = c; }     // first max (c ascending)
    }
    for (int off = 4; off; off >>= 1) {
      float ov = __shfl_xor(bv, off, 8);
      int   oc = __shfl_xor(bc, off, 8);
      if (ov > bv || (ov == bv && oc < bc)) { bv = ov; bc = oc; }
    }
    #pragma unroll
    for (int i = 0; i < 4; ++i) {
      int c = lane + 8 * i, col = d * 32 + c;
      float zv = 0.0f;
      if (c == bc) zv = __fsub_rn(__fadd_rn(1.0f, p[i]), p[i]);  // (1+p)-p
      out[NOUT + ob + col] = zv;
      XZ[(size_t)b * 1040 + col] = zv;
    }
    if (tid < 6 && (t + 1) < 64)
      XZ[(size_t)b * 1040 + 1024 + tid] = actions[((size_t)b * 64 + (t + 1)) * 6 + tid];
  }
}

__global__ __launch_bounds__(256) void init_k(const float* h_init, const float* z_init,
                                              const float* actions, float* H, float* XZ)
{
  int b = blockIdx.x, tid = threadIdx.x;
  #pragma unroll
  for (int j = 0; j < 4; ++j) {
    int n = tid + j * 256;
    H [(size_t)b * 1024 + n] = h_init[(size_t)b * 1024 + n];
    XZ[(size_t)b * 1040 + n] = z_init[(size_t)b * 1024 + n];
  }
  if (tid < 6) XZ[(size_t)b * 1040 + 1024 + tid] = actions[(size_t)b * 64 * 6 + tid];
}

extern "C" void kernel_launch(void* const* d_in, const int* in_sizes, int n_in,
                              void* d_out, int out_size, void* d_ws, size_t ws_size,
                              hipStream_t stream)
{
  const float* embeds  = (const float*)d_in[0];
  const float* actions = (const float*)d_in[1];
  const float* h_init  = (const float*)d_in[2];
  const float* z_init  = (const float*)d_in[3];
  const float* W_pre   = (const float*)d_in[4];
  const float* b_pre   = (const float*)d_in[5];
  const float* g_pre   = (const float*)d_in[6];
  const float* be_pre  = (const float*)d_in[7];
  const float* W_ih    = (const float*)d_in[8];
  const float* W_hh    = (const float*)d_in[9];
  const float* b_ih    = (const float*)d_in[10];
  const float* b_hh    = (const float*)d_in[11];
  const float* g_gn    = (const float*)d_in[12];
  const float* b_gn    = (const float*)d_in[13];
  const float* Wp1     = (const float*)d_in[14];
  const float* bp1     = (const float*)d_in[15];
  const float* gp      = (const float*)d_in[16];
  const float* bpn     = (const float*)d_in[17];
  const float* Wp2     = (const float*)d_in[18];
  const float* bp2     = (const float*)d_in[19];
  const float* Wq1     = (const float*)d_in[20];
  const float* bq1     = (const float*)d_in[21];
  const float* gq      = (const float*)d_in[22];
  const float* bqn     = (const float*)d_in[23];
  const float* Wq2     = (const float*)d_in[24];
  const float* bq2     = (const float*)d_in[25];
  // d_in[26] = u_prior: unused (prior z discarded by reference)
  const float* u_post  = (const float*)d_in[27];
  float* out           = (float*)d_out;

  // f32 workspace, disjoint: ~16.8 MB
  float* W0   = (float*)d_ws;
  float* H    = W0;                  // 262144
  float* XZ   = W0 + 262144;         // 266240 (row stride 1040: z|a|pad)
  float* XPRE = W0 + 528384;         // 262144
  float* PREY = W0 + 790528;         // 262144
  float* GX   = W0 + 1052672;        // 786432
  float* GH   = W0 + 1839104;        // 786432
  float* Y1   = W0 + 2625536;        // 262144
  float* YQ   = W0 + 2887680;        // 262144
  float* P1A  = W0 + 3149824;        // 262144
  float* Q1A  = W0 + 3411968;        // 262144
  float* Y2   = W0 + 3674112;        // 262144
  float* YQ2  = W0 + 3936256;        // 262144

  hipLaunchKernelGGL(init_k, dim3(256), dim3(256), 0, stream, h_init, z_init, actions, H, XZ);

  for (int t = 0; t < 64; ++t) {
    // 1) PREY = [z|a] @ W_pre^T   (K=1030)
    GArg pre{XZ, 1040, XZ, 1040, 1030, W_pre, 1030, PREY, 1024, 1030};
    hipLaunchKernelGGL(gemm_k, dim3(16, 4, 1), dim3(256), 0, stream, pre, pre);
    // 2) XPRE = silu(LN(PREY + b_pre))
    hipLaunchKernelGGL(lnsilu_k, dim3(64, 1), dim3(256), 0, stream,
                       PREY, b_pre, g_pre, be_pre, XPRE,
                       PREY, b_pre, g_pre, be_pre, XPRE);
    // 3) GX = XPRE @ W_ih^T ; GH = H @ W_hh^T   (N=3072)
    GArg gx{XPRE, 1024, XPRE, 1024, 1024, W_ih, 1024, GX, 3072, 1024};
    GArg gh{H,    1024, H,    1024, 1024, W_hh, 1024, GH, 3072, 1024};
    hipLaunchKernelGGL(gemm_k, dim3(48, 4, 2), dim3(256), 0, stream, gx, gh);
    // 4) GRU combine + LN -> H, hs
    hipLaunchKernelGGL(gru_k, dim3(64), dim3(256), 0, stream,
                       GX, GH, H, b_ih, b_hh, g_gn, b_gn, out, t);
    // 5) Y1 = H @ Wp1^T ; YQ = [H|e_t] @ Wq1^T (two-source K=2048)
    GArg p1{H, 1024, H, 1024, 1024, Wp1, 1024, Y1, 1024, 1024};
    GArg q1{H, 1024, embeds + (size_t)t * 1024, 65536, 1024, Wq1, 2048, YQ, 1024, 2048};
    hipLaunchKernelGGL(gemm_k, dim3(16, 4, 2), dim3(256), 0, stream, p1, q1);
    // 6) P1A = silu(LN(Y1+bp1)) ; Q1A = silu(LN(YQ+bq1))
    hipLaunchKernelGGL(lnsilu_k, dim3(64, 2), dim3(256), 0, stream,
                       Y1, bp1, gp, bpn, P1A,
                       YQ, bq1, gq, bqn, Q1A);
    // 7) Y2 = P1A @ Wp2^T ; YQ2 = Q1A @ Wq2^T
    GArg p2{P1A, 1024, P1A, 1024, 1024, Wp2, 1024, Y2,  1024, 1024};
    GArg q2{Q1A, 1024, Q1A, 1024, 1024, Wq2, 1024, YQ2, 1024, 1024};
    hipLaunchKernelGGL(gemm_k, dim3(16, 4, 2), dim3(256), 0, stream, p2, q2);
    // 8) softmax+unimix (+gumbel argmax), pp/qp/zs, next [z|a]
    hipLaunchKernelGGL(sample_k, dim3(256, 2), dim3(256), 0, stream,
                       Y2, YQ2, bp2, bq2, u_post, actions, XZ, out, t);
  }
}

// Round 7
// 20372.171 us; speedup vs baseline: 2.2925x; 2.2925x over previous
//
#include <hip/hip_runtime.h>
#include <hip/hip_bf16.h>
#include <math.h>

// RSSM scan — numpy-realization f32 (PASSING cell, frozen numerics):
//   GEMM: OpenBLAS sgemm replica — K panels of 384 (24 BK-tiles), per-element
//         single-acc k-ascending fmaf chain per panel, panels folded ascending
//         ((p0+p1)+p2) with __fadd_rn — now split across blockIdx.z, folded by
//         the CONSUMER in the same order (bit-identical).
//   Reductions: numpy pairwise replica. Transcendentals: CR f32 via f64.
// Perf round: K-panel block-split (CU coverage) + ds_read_b128 fragments +
// padded LDS [16][68] + float4 C-stores. Outputs f32.

struct GArg {
  const float* A0; int lda0;        // K-segment 0
  const float* A1; int lda1;        // K-segment 1 (k >= kSplit)
  int kSplit;
  const float* W; int ldw;          // weights (N x K) row-major f32
  float* C; int N; int K;           // C gets panel s at C + s*256*N
};

__device__ __forceinline__ float exp_cr(float x)  { return (float)exp((double)x); }
__device__ __forceinline__ float log_cr(float x)  { return (float)log((double)x); }
__device__ __forceinline__ float tanh_cr(float x) { return (float)tanh((double)x); }

__device__ __forceinline__ float sigmoid_cr(float x) {
  float e = exp_cr(-x);
  float d = __fadd_rn(1.0f, e);
  return __fdiv_rn(1.0f, d);
}

// One 384-k panel (24 BK=16 tiles) of C[m,n] = sum_k A[m,k]*W[n,k].
// Tile 64x64; thread owns contiguous 4x4 outputs -> 2x ds_read_b128 per kk.
__global__ __launch_bounds__(256) void gemm_k(GArg g0, GArg g1, int zSplit) {
  int z = blockIdx.z;
  GArg G; int s;
  if (z < zSplit) { G = g0; s = z; } else { G = g1; s = z - zSplit; }
  int n0 = blockIdx.x * 64;
  if (n0 >= G.N) return;
  int m0 = blockIdx.y * 64;

  __shared__ float As[16][68];   // [k][m], +4 pad keeps 16B align, 2-way max
  __shared__ float Bs[16][68];   // [k][n]

  int tid = threadIdx.x;
  int tx = tid & 15, ty = tid >> 4;       // output block: rows ty*4.., cols tx*4..
  int sm = tid >> 2, skb = (tid & 3) * 4; // staging: col sm, k-sub skb..skb+3

  float acc[4][4];
  #pragma unroll
  for (int j = 0; j < 4; ++j)
    #pragma unroll
    for (int i = 0; i < 4; ++i) acc[j][i] = 0.0f;

  int nt = (G.K + 15) >> 4;
  int t0 = s * 24, t1 = min(nt, t0 + 24);

  for (int kt = t0; kt < t1; ++kt) {
    int kb = kt * 16;
    #pragma unroll
    for (int i = 0; i < 4; ++i) {
      int k = kb + skb + i;
      float av = 0.0f, wv = 0.0f;
      if (k < G.K) {
        if (k < G.kSplit) av = G.A0[(size_t)(m0 + sm) * G.lda0 + k];
        else              av = G.A1[(size_t)(m0 + sm) * G.lda1 + (k - G.kSplit)];
        wv = G.W[(size_t)(n0 + sm) * G.ldw + k];
      }
      As[skb + i][sm] = av;
      Bs[skb + i][sm] = wv;
    }
    __syncthreads();
    #pragma unroll
    for (int kk = 0; kk < 16; ++kk) {
      float4 av = *(const float4*)&As[kk][ty * 4];
      float4 bv = *(const float4*)&Bs[kk][tx * 4];
      float a[4] = {av.x, av.y, av.z, av.w};
      float b[4] = {bv.x, bv.y, bv.z, bv.w};
      #pragma unroll
      for (int j = 0; j < 4; ++j)
        #pragma unroll
        for (int i = 0; i < 4; ++i)
          acc[j][i] = fmaf(a[j], b[i], acc[j][i]);   // k-ascending chain
    }
    __syncthreads();
  }

  float* Cp = G.C + (size_t)s * 256 * G.N;
  #pragma unroll
  for (int j = 0; j < 4; ++j) {
    float4 v = make_float4(acc[j][0], acc[j][1], acc[j][2], acc[j][3]);
    *(float4*)&Cp[(size_t)(m0 + ty * 4 + j) * G.N + n0 + tx * 4] = v;
  }
}

// numpy pairwise sum over 1024: lane kb=l>>3,j=l&7 owns a[kb*128+8i+j] i=0..15
// sequential; combine xor 1,2,4 (within 128-block tree), xor 8,16,32 (blocks).
__device__ __forceinline__ float pairwise1024(const float* v /*16 per lane*/) {
  float r = v[0];
  #pragma unroll
  for (int i = 1; i < 16; ++i) r = __fadd_rn(r, v[i]);
  r = __fadd_rn(r, __shfl_xor(r, 1));
  r = __fadd_rn(r, __shfl_xor(r, 2));
  r = __fadd_rn(r, __shfl_xor(r, 4));
  r = __fadd_rn(r, __shfl_xor(r, 8));
  r = __fadd_rn(r, __shfl_xor(r, 16));
  r = __fadd_rn(r, __shfl_xor(r, 32));
  return r;
}

// ---- LN + SiLU rows of 1024; folds S panels (stride 262144) + bias ----
__global__ __launch_bounds__(256) void lnsilu_k(
  const float* Y0, int S0, const float* bias0, const float* g0, const float* be0, float* O0,
  const float* Y1p, int S1, const float* bias1, const float* g1, const float* be1, float* O1)
{
  int pair = blockIdx.y;
  const float* Y = pair ? Y1p : Y0;
  int S = pair ? S1 : S0;
  const float* bias = pair ? bias1 : bias0;
  const float* gg   = pair ? g1 : g0;
  const float* be   = pair ? be1 : be0;
  float* O = pair ? O1 : O0;

  int tid = threadIdx.x;
  int row = blockIdx.x * 4 + (tid >> 6);
  int lane = tid & 63, kb = lane >> 3, j = lane & 7;

  float xv[16];
  #pragma unroll
  for (int i = 0; i < 16; ++i) {
    int n = kb * 128 + 8 * i + j;
    size_t idx = (size_t)row * 1024 + n;
    float x = Y[idx];
    for (int ss = 1; ss < S; ++ss) x = __fadd_rn(x, Y[(size_t)ss * 262144 + idx]);
    xv[i] = __fadd_rn(x, bias[n]);
  }
  float mean = __fmul_rn(pairwise1024(xv), 0.0009765625f);
  float d[16], sq[16];
  #pragma unroll
  for (int i = 0; i < 16; ++i) { d[i] = __fsub_rn(xv[i], mean); sq[i] = __fmul_rn(d[i], d[i]); }
  float var = __fmul_rn(pairwise1024(sq), 0.0009765625f);
  float s = __fsqrt_rn(__fadd_rn(var, (float)1e-5));
  float rstd = __fdiv_rn(1.0f, s);
  #pragma unroll
  for (int i = 0; i < 16; ++i) {
    int n = kb * 128 + 8 * i + j;
    float t = __fmul_rn(__fmul_rn(d[i], rstd), gg[n]);
    t = __fadd_rn(t, be[n]);
    O[(size_t)row * 1024 + n] = __fmul_rn(t, sigmoid_cr(t));   // silu
  }
}

// ---- GRU combine + LN; folds 3 panels (stride 786432) per gate source ----
__global__ __launch_bounds__(256) void gru_k(
  const float* GX, const float* GH, float* H,
  const float* b_ih, const float* b_hh, const float* g_gn, const float* b_gn,
  float* out, int t)
{
  int tid = threadIdx.x;
  int row = blockIdx.x * 4 + (tid >> 6);
  int lane = tid & 63, kb = lane >> 3, j = lane & 7;

  float hv[16];
  #pragma unroll
  for (int i = 0; i < 16; ++i) {
    int n = kb * 128 + 8 * i + j;
    size_t i0 = (size_t)row * 3072 + n;
    #define FOLD3(P, off) __fadd_rn(__fadd_rn((P)[off], (P)[786432 + (off)]), (P)[1572864 + (off)])
    float xr = __fadd_rn(FOLD3(GX, i0),        b_ih[n]);
    float xu = __fadd_rn(FOLD3(GX, i0 + 1024), b_ih[n + 1024]);
    float xn = __fadd_rn(FOLD3(GX, i0 + 2048), b_ih[n + 2048]);
    float hr = __fadd_rn(FOLD3(GH, i0),        b_hh[n]);
    float hu = __fadd_rn(FOLD3(GH, i0 + 1024), b_hh[n + 1024]);
    float hn = __fadd_rn(FOLD3(GH, i0 + 2048), b_hh[n + 2048]);
    #undef FOLD3
    float r = sigmoid_cr(__fadd_rn(xr, hr));
    float u = sigmoid_cr(__fadd_rn(xu, hu));
    float nn = tanh_cr(__fadd_rn(xn, __fmul_rn(r, hn)));
    float h2 = __fadd_rn(__fmul_rn(__fsub_rn(1.0f, u), nn),
                         __fmul_rn(u, H[(size_t)row * 1024 + n]));
    hv[i] = h2;
  }
  float mean = __fmul_rn(pairwise1024(hv), 0.0009765625f);
  float d[16], sq[16];
  #pragma unroll
  for (int i = 0; i < 16; ++i) { d[i] = __fsub_rn(hv[i], mean); sq[i] = __fmul_rn(d[i], d[i]); }
  float var = __fmul_rn(pairwise1024(sq), 0.0009765625f);
  float s = __fsqrt_rn(__fadd_rn(var, (float)1e-5));
  float rstd = __fdiv_rn(1.0f, s);
  #pragma unroll
  for (int i = 0; i < 16; ++i) {
    int n = kb * 128 + 8 * i + j;
    float h3 = __fadd_rn(__fmul_rn(__fmul_rn(d[i], rstd), g_gn[n]), b_gn[n]);
    H[(size_t)row * 1024 + n] = h3;
    out[((size_t)row * 64 + t) * 1024 + n] = h3;
  }
}

// ---- softmax+unimix (+gumbel argmax posterior); folds 3 panels ----
__global__ __launch_bounds__(256) void sample_k(
  const float* Yp, const float* Yq, const float* bp2, const float* bq2,
  const float* u_post, const float* actions, float* XZ,
  float* out, int t)
{
  const size_t NOUT = 16777216ull;
  int pair = blockIdx.y, b = blockIdx.x, tid = threadIdx.x;
  int d = tid >> 3, lane = tid & 7;           // 32 dists x 8 lanes, 4 cats/lane
  const float* Y = pair ? Yq : Yp;
  const float* bias = pair ? bq2 : bp2;
  const float C0 = (float)(1.0 - 0.01);
  const float C1 = (float)(0.01 / 32.0);

  float lg[4];
  #pragma unroll
  for (int i = 0; i < 4; ++i) {
    int col = d * 32 + lane + 8 * i;          // c = lane + 8i
    size_t idx = (size_t)b * 1024 + col;
    float x = __fadd_rn(__fadd_rn(Y[idx], Y[262144 + idx]), Y[524288 + idx]);
    lg[i] = __fadd_rn(x, bias[col]);
  }
  float mx = fmaxf(fmaxf(lg[0], lg[1]), fmaxf(lg[2], lg[3]));
  for (int off = 4; off; off >>= 1) mx = fmaxf(mx, __shfl_xor(mx, off, 8));

  float e[4];
  #pragma unroll
  for (int i = 0; i < 4; ++i) e[i] = exp_cr(__fsub_rn(lg[i], mx));
  float ssum = e[0];
  ssum = __fadd_rn(ssum, e[1]);
  ssum = __fadd_rn(ssum, e[2]);
  ssum = __fadd_rn(ssum, e[3]);
  ssum = __fadd_rn(ssum, __shfl_xor(ssum, 1, 8));
  ssum = __fadd_rn(ssum, __shfl_xor(ssum, 2, 8));
  ssum = __fadd_rn(ssum, __shfl_xor(ssum, 4, 8));

  float p[4];
  #pragma unroll
  for (int i = 0; i < 4; ++i) {
    float pr = __fdiv_rn(e[i], ssum);
    p[i] = __fadd_rn(__fmul_rn(C0, pr), C1);
  }

  size_t ob = ((size_t)b * 64 + t) * 1024;
  if (!pair) {
    #pragma unroll
    for (int i = 0; i < 4; ++i)
      out[2 * NOUT + ob + (d * 32 + lane + 8 * i)] = p[i];
  } else {
    float bv = -3.4e38f; int bc = 33;
    #pragma unroll
    for (int i = 0; i < 4; ++i) {
      int c = lane + 8 * i, col = d * 32 + c;
      out[3 * NOUT + ob + col] = p[i];
      float uu = u_post[((size_t)t * 256 + b) * 1024 + col];
      float l1 = log_cr(uu);
      float v1 = -l1;
      float l2 = log_cr(v1);
      float gu = -l2;
      float lp = log_cr(p[i]);
      float val = __fadd_rn(lp, gu);
      if (val > bv) { bv = val; bc = c; }     // first max (c ascending)
    }
    for (int off = 4; off; off >>= 1) {
      float ov = __shfl_xor(bv, off, 8);
      int   oc = __shfl_xor(bc, off, 8);
      if (ov > bv || (ov == bv && oc < bc)) { bv = ov; bc = oc; }
    }
    #pragma unroll
    for (int i = 0; i < 4; ++i) {
      int c = lane + 8 * i, col = d * 32 + c;
      float zv = 0.0f;
      if (c == bc) zv = __fsub_rn(__fadd_rn(1.0f, p[i]), p[i]);
      out[NOUT + ob + col] = zv;
      XZ[(size_t)b * 1040 + col] = zv;
    }
    if (tid < 6 && (t + 1) < 64)
      XZ[(size_t)b * 1040 + 1024 + tid] = actions[((size_t)b * 64 + (t + 1)) * 6 + tid];
  }
}

__global__ __launch_bounds__(256) void init_k(const float* h_init, const float* z_init,
                                              const float* actions, float* H, float* XZ)
{
  int b = blockIdx.x, tid = threadIdx.x;
  #pragma unroll
  for (int j = 0; j < 4; ++j) {
    int n = tid + j * 256;
    H [(size_t)b * 1024 + n] = h_init[(size_t)b * 1024 + n];
    XZ[(size_t)b * 1040 + n] = z_init[(size_t)b * 1024 + n];
  }
  if (tid < 6) XZ[(size_t)b * 1040 + 1024 + tid] = actions[(size_t)b * 64 * 6 + tid];
}

extern "C" void kernel_launch(void* const* d_in, const int* in_sizes, int n_in,
                              void* d_out, int out_size, void* d_ws, size_t ws_size,
                              hipStream_t stream)
{
  const float* embeds  = (const float*)d_in[0];
  const float* actions = (const float*)d_in[1];
  const float* h_init  = (const float*)d_in[2];
  const float* z_init  = (const float*)d_in[3];
  const float* W_pre   = (const float*)d_in[4];
  const float* b_pre   = (const float*)d_in[5];
  const float* g_pre   = (const float*)d_in[6];
  const float* be_pre  = (const float*)d_in[7];
  const float* W_ih    = (const float*)d_in[8];
  const float* W_hh    = (const float*)d_in[9];
  const float* b_ih    = (const float*)d_in[10];
  const float* b_hh    = (const float*)d_in[11];
  const float* g_gn    = (const float*)d_in[12];
  const float* b_gn    = (const float*)d_in[13];
  const float* Wp1     = (const float*)d_in[14];
  const float* bp1     = (const float*)d_in[15];
  const float* gp      = (const float*)d_in[16];
  const float* bpn     = (const float*)d_in[17];
  const float* Wp2     = (const float*)d_in[18];
  const float* bp2     = (const float*)d_in[19];
  const float* Wq1     = (const float*)d_in[20];
  const float* bq1     = (const float*)d_in[21];
  const float* gq      = (const float*)d_in[22];
  const float* bqn     = (const float*)d_in[23];
  const float* Wq2     = (const float*)d_in[24];
  const float* bq2     = (const float*)d_in[25];
  // d_in[26] = u_prior: unused
  const float* u_post  = (const float*)d_in[27];
  float* out           = (float*)d_out;

  // f32 workspace with lifetime aliasing: 6,295,552 floats = 25.2 MB
  float* W0   = (float*)d_ws;
  float* H    = W0;                       // 262144
  float* XZ   = W0 + 262144;              // 266240 (row stride 1040)
  float* XPRE = W0 + 528384;              // 262144
  float* PREY = W0 + 790528;              // 786432 (3 panels)
  float* A0   = W0 + 1576960;             // region A: 4718592
  float* GX   = A0;                       // 2359296 (3 panels x 786432)  [steps 3-4]
  float* GH   = A0 + 2359296;             // 2359296                      [steps 3-4]
  float* Y1   = A0;                       // 786432 (3 panels)            [steps 5-6]
  float* YQ   = A0 + 786432;              // 1572864 (6 panels)           [steps 5-6]
  float* Y2   = A0 + 2359296;             // 786432 (3 panels)            [steps 7-8]
  float* YQ2  = A0 + 3145728;             // 786432 (3 panels)            [steps 7-8]
  float* P1A  = A0 + 3932160;             // 262144                       [steps 6-7]
  float* Q1A  = A0 + 4194304;             // 262144                       [steps 6-7]

  hipLaunchKernelGGL(init_k, dim3(256), dim3(256), 0, stream, h_init, z_init, actions, H, XZ);

  for (int t = 0; t < 64; ++t) {
    // 1) PREY[s] = panel_s([z|a] @ W_pre^T)   K=1030, 3 panels
    GArg pre{XZ, 1040, XZ, 1040, 1030, W_pre, 1030, PREY, 1024, 1030};
    hipLaunchKernelGGL(gemm_k, dim3(16, 4, 3), dim3(256), 0, stream, pre, pre, 3);
    // 2) XPRE = silu(LN(fold3(PREY) + b_pre))
    hipLaunchKernelGGL(lnsilu_k, dim3(64, 1), dim3(256), 0, stream,
                       PREY, 3, b_pre, g_pre, be_pre, XPRE,
                       PREY, 3, b_pre, g_pre, be_pre, XPRE);
    // 3) GX[s] = panel_s(XPRE @ W_ih^T); GH[s] = panel_s(H @ W_hh^T)  N=3072
    GArg gx{XPRE, 1024, XPRE, 1024, 1024, W_ih, 1024, GX, 3072, 1024};
    GArg gh{H,    1024, H,    1024, 1024, W_hh, 1024, GH, 3072, 1024};
    hipLaunchKernelGGL(gemm_k, dim3(48, 4, 6), dim3(256), 0, stream, gx, gh, 3);
    // 4) GRU combine (fold3 each) + LN -> H, hs
    hipLaunchKernelGGL(gru_k, dim3(64), dim3(256), 0, stream,
                       GX, GH, H, b_ih, b_hh, g_gn, b_gn, out, t);
    // 5) Y1[s] = panel_s(H @ Wp1^T) (3); YQ[s] = panel_s([H|e_t] @ Wq1^T) (6, K=2048)
    GArg p1{H, 1024, H, 1024, 1024, Wp1, 1024, Y1, 1024, 1024};
    GArg q1{H, 1024, embeds + (size_t)t * 1024, 65536, 1024, Wq1, 2048, YQ, 1024, 2048};
    hipLaunchKernelGGL(gemm_k, dim3(16, 4, 9), dim3(256), 0, stream, p1, q1, 3);
    // 6) P1A = silu(LN(fold3(Y1)+bp1)); Q1A = silu(LN(fold6(YQ)+bq1))
    hipLaunchKernelGGL(lnsilu_k, dim3(64, 2), dim3(256), 0, stream,
                       Y1, 3, bp1, gp, bpn, P1A,
                       YQ, 6, bq1, gq, bqn, Q1A);
    // 7) Y2[s] = panel_s(P1A @ Wp2^T); YQ2[s] = panel_s(Q1A @ Wq2^T)
    GArg p2{P1A, 1024, P1A, 1024, 1024, Wp2, 1024, Y2,  1024, 1024};
    GArg q2{Q1A, 1024, Q1A, 1024, 1024, Wq2, 1024, YQ2, 1024, 1024};
    hipLaunchKernelGGL(gemm_k, dim3(16, 4, 6), dim3(256), 0, stream, p2, q2, 3);
    // 8) softmax+unimix (+gumbel argmax), fold3, pp/qp/zs, next [z|a]
    hipLaunchKernelGGL(sample_k, dim3(256, 2), dim3(256), 0, stream,
                       Y2, YQ2, bp2, bq2, u_post, actions, XZ, out, t);
  }
}

// Round 8
// 12428.567 us; speedup vs baseline: 3.7577x; 1.6391x over previous
//
#include <hip/hip_runtime.h>
#include <hip/hip_bf16.h>
#include <math.h>

// RSSM scan — numpy-realization f32 (PASSING cell, frozen numerics on the
// POSTERIOR/recurrent path):
//   GEMM: OpenBLAS sgemm replica — K panels of 384 (24 BK-tiles), per-element
//         single-acc k-ascending fmaf chain per panel, panels folded ascending
//         by the consumer. Reductions: numpy pairwise replica. CR transcendentals.
// Perf round: double-buffered staging (1 barrier/tile, global-latency overlap),
// b128 ds_writes, prior chain hoisted out of the serial loop into batched
// post-loop GEMMs (value-safe: no argmax in prior path), elementwise kernels
// widened to 256 blocks. Outputs f32: hs | zs | pp | qp.

struct GArg {
  const float* A0; int lda0;        // K-segment 0
  const float* A1; int lda1;        // K-segment 1 (k >= kSplit)
  int kSplit;
  const float* W; int ldw;          // weights (N x K) row-major f32
  float* C; int N; int K;           // panel s written at C + s*256*N
};

__device__ __forceinline__ float exp_cr(float x)  { return (float)exp((double)x); }
__device__ __forceinline__ float log_cr(float x)  { return (float)log((double)x); }
__device__ __forceinline__ float tanh_cr(float x) { return (float)tanh((double)x); }

__device__ __forceinline__ float sigmoid_cr(float x) {
  float e = exp_cr(-x);
  float d = __fadd_rn(1.0f, e);
  return __fdiv_rn(1.0f, d);
}

// One panel (tpp BK=16 tiles) of C[m,n] = sum_k A[m,k]*W[n,k]. Tile 64x64,
// thread owns 4x4 outputs. Double-buffered LDS; chains bit-identical to r6/r7.
__global__ __launch_bounds__(256) void gemm_k(GArg g0, GArg g1, int zSplit, int tpp) {
  int z = blockIdx.z;
  GArg G; int s;
  if (z < zSplit) { G = g0; s = z; } else { G = g1; s = z - zSplit; }
  int n0 = blockIdx.x * 64;
  if (n0 >= G.N) return;
  int m0 = blockIdx.y * 64;

  __shared__ float As[2][16][68];   // [buf][k][m]
  __shared__ float Bs[2][16][68];   // [buf][k][n]

  int tid = threadIdx.x;
  int tx = tid & 15, ty = tid >> 4;   // compute: rows ty*4.., cols tx*4..
                                      // staging: k-col tx, row-group ty*4..

  float acc[4][4];
  #pragma unroll
  for (int j = 0; j < 4; ++j)
    #pragma unroll
    for (int i = 0; i < 4; ++i) acc[j][i] = 0.0f;

  int nt = (G.K + 15) >> 4;
  int t0 = s * tpp, t1 = min(nt, t0 + tpp);

  float a[4], w[4];

  auto stage_load = [&](int kt) {
    int k = kt * 16 + tx;
    if (k < G.K) {
      if (k < G.kSplit) {
        const float* Ap = G.A0 + (size_t)(m0 + ty * 4) * G.lda0 + k;
        #pragma unroll
        for (int i = 0; i < 4; ++i) a[i] = Ap[(size_t)i * G.lda0];
      } else {
        const float* Ap = G.A1 + (size_t)(m0 + ty * 4) * G.lda1 + (k - G.kSplit);
        #pragma unroll
        for (int i = 0; i < 4; ++i) a[i] = Ap[(size_t)i * G.lda1];
      }
      const float* Wp = G.W + (size_t)(n0 + ty * 4) * G.ldw + k;
      #pragma unroll
      for (int i = 0; i < 4; ++i) w[i] = Wp[(size_t)i * G.ldw];
    } else {
      #pragma unroll
      for (int i = 0; i < 4; ++i) { a[i] = 0.0f; w[i] = 0.0f; }
    }
  };
  auto stage_write = [&](int b) {
    *(float4*)&As[b][tx][ty * 4] = make_float4(a[0], a[1], a[2], a[3]);
    *(float4*)&Bs[b][tx][ty * 4] = make_float4(w[0], w[1], w[2], w[3]);
  };
  auto compute = [&](int b) {
    #pragma unroll
    for (int kk = 0; kk < 16; ++kk) {
      float4 av = *(const float4*)&As[b][kk][ty * 4];
      float4 bv = *(const float4*)&Bs[b][kk][tx * 4];
      float aa[4] = {av.x, av.y, av.z, av.w};
      float bb[4] = {bv.x, bv.y, bv.z, bv.w};
      #pragma unroll
      for (int j = 0; j < 4; ++j)
        #pragma unroll
        for (int i = 0; i < 4; ++i)
          acc[j][i] = fmaf(aa[j], bb[i], acc[j][i]);   // k-ascending chain
    }
  };

  stage_load(t0);
  stage_write(0);
  __syncthreads();
  int cur = 0;
  for (int kt = t0; kt < t1; ++kt) {
    if (kt + 1 < t1) {
      stage_load(kt + 1);       // global loads in flight during compute
      compute(cur);
      stage_write(cur ^ 1);     // waits vmcnt; other buffer, no race
      __syncthreads();
      cur ^= 1;
    } else {
      compute(cur);
    }
  }

  float* Cp = G.C + (size_t)s * 256 * G.N;
  #pragma unroll
  for (int j = 0; j < 4; ++j) {
    float4 v = make_float4(acc[j][0], acc[j][1], acc[j][2], acc[j][3]);
    *(float4*)&Cp[(size_t)(m0 + ty * 4 + j) * G.N + n0 + tx * 4] = v;
  }
}

// numpy pairwise sum over 1024 (frozen): lane kb=l>>3,j=l&7 owns
// a[kb*128+8i+j], i ascending; combine xor 1,2,4 then 8,16,32.
__device__ __forceinline__ float pairwise1024(const float* v /*16 per lane*/) {
  float r = v[0];
  #pragma unroll
  for (int i = 1; i < 16; ++i) r = __fadd_rn(r, v[i]);
  r = __fadd_rn(r, __shfl_xor(r, 1));
  r = __fadd_rn(r, __shfl_xor(r, 2));
  r = __fadd_rn(r, __shfl_xor(r, 4));
  r = __fadd_rn(r, __shfl_xor(r, 8));
  r = __fadd_rn(r, __shfl_xor(r, 16));
  r = __fadd_rn(r, __shfl_xor(r, 32));
  return r;
}

// ---- LN + SiLU, one wave per row; folds S panels (stride 262144) + bias ----
__global__ __launch_bounds__(64) void lnsilu_k(
  const float* Y, int S, const float* bias, const float* gg, const float* be, float* O)
{
  int row = blockIdx.x, lane = threadIdx.x;
  int kb = lane >> 3, j = lane & 7;

  float xv[16];
  #pragma unroll
  for (int i = 0; i < 16; ++i) {
    int n = kb * 128 + 8 * i + j;
    size_t idx = (size_t)row * 1024 + n;
    float x = Y[idx];
    for (int ss = 1; ss < S; ++ss) x = __fadd_rn(x, Y[(size_t)ss * 262144 + idx]);
    xv[i] = __fadd_rn(x, bias[n]);
  }
  float mean = __fmul_rn(pairwise1024(xv), 0.0009765625f);
  float d[16], sq[16];
  #pragma unroll
  for (int i = 0; i < 16; ++i) { d[i] = __fsub_rn(xv[i], mean); sq[i] = __fmul_rn(d[i], d[i]); }
  float var = __fmul_rn(pairwise1024(sq), 0.0009765625f);
  float s = __fsqrt_rn(__fadd_rn(var, (float)1e-5));
  float rstd = __fdiv_rn(1.0f, s);
  #pragma unroll
  for (int i = 0; i < 16; ++i) {
    int n = kb * 128 + 8 * i + j;
    float t = __fmul_rn(__fmul_rn(d[i], rstd), gg[n]);
    t = __fadd_rn(t, be[n]);
    O[(size_t)row * 1024 + n] = __fmul_rn(t, sigmoid_cr(t));   // silu
  }
}

// ---- GRU combine + LN; one wave per row; folds 3 panels (stride 786432) ----
__global__ __launch_bounds__(64) void gru_k(
  const float* GX, const float* GH, float* H,
  const float* b_ih, const float* b_hh, const float* g_gn, const float* b_gn,
  float* out, int t)
{
  int row = blockIdx.x, lane = threadIdx.x;
  int kb = lane >> 3, j = lane & 7;

  float hv[16];
  #pragma unroll
  for (int i = 0; i < 16; ++i) {
    int n = kb * 128 + 8 * i + j;
    size_t i0 = (size_t)row * 3072 + n;
    #define FOLD3(P, off) __fadd_rn(__fadd_rn((P)[off], (P)[786432 + (off)]), (P)[1572864 + (off)])
    float xr = __fadd_rn(FOLD3(GX, i0),        b_ih[n]);
    float xu = __fadd_rn(FOLD3(GX, i0 + 1024), b_ih[n + 1024]);
    float xn = __fadd_rn(FOLD3(GX, i0 + 2048), b_ih[n + 2048]);
    float hr = __fadd_rn(FOLD3(GH, i0),        b_hh[n]);
    float hu = __fadd_rn(FOLD3(GH, i0 + 1024), b_hh[n + 1024]);
    float hn = __fadd_rn(FOLD3(GH, i0 + 2048), b_hh[n + 2048]);
    #undef FOLD3
    float r = sigmoid_cr(__fadd_rn(xr, hr));
    float u = sigmoid_cr(__fadd_rn(xu, hu));
    float nn = tanh_cr(__fadd_rn(xn, __fmul_rn(r, hn)));
    float h2 = __fadd_rn(__fmul_rn(__fsub_rn(1.0f, u), nn),
                         __fmul_rn(u, H[(size_t)row * 1024 + n]));
    hv[i] = h2;
  }
  float mean = __fmul_rn(pairwise1024(hv), 0.0009765625f);
  float d[16], sq[16];
  #pragma unroll
  for (int i = 0; i < 16; ++i) { d[i] = __fsub_rn(hv[i], mean); sq[i] = __fmul_rn(d[i], d[i]); }
  float var = __fmul_rn(pairwise1024(sq), 0.0009765625f);
  float s = __fsqrt_rn(__fadd_rn(var, (float)1e-5));
  float rstd = __fdiv_rn(1.0f, s);
  #pragma unroll
  for (int i = 0; i < 16; ++i) {
    int n = kb * 128 + 8 * i + j;
    float h3 = __fadd_rn(__fmul_rn(__fmul_rn(d[i], rstd), g_gn[n]), b_gn[n]);
    H[(size_t)row * 1024 + n] = h3;
    out[((size_t)row * 64 + t) * 1024 + n] = h3;
  }
}

// ---- posterior softmax+unimix+gumbel argmax; qp/zs, z-carry (frozen) ----
__global__ __launch_bounds__(256) void sample_post_k(
  const float* Yq, const float* bq2, const float* u_post, const float* actions,
  float* XZ, float* out, int t)
{
  const size_t NOUT = 16777216ull;
  int b = blockIdx.x, tid = threadIdx.x;
  int d = tid >> 3, lane = tid & 7;           // 32 dists x 8 lanes, 4 cats/lane
  const float C0 = (float)(1.0 - 0.01);
  const float C1 = (float)(0.01 / 32.0);

  float lg[4];
  #pragma unroll
  for (int i = 0; i < 4; ++i) {
    int col = d * 32 + lane + 8 * i;          // c = lane + 8i
    size_t idx = (size_t)b * 1024 + col;
    float x = __fadd_rn(__fadd_rn(Yq[idx], Yq[262144 + idx]), Yq[524288 + idx]);
    lg[i] = __fadd_rn(x, bq2[col]);
  }
  float mx = fmaxf(fmaxf(lg[0], lg[1]), fmaxf(lg[2], lg[3]));
  for (int off = 4; off; off >>= 1) mx = fmaxf(mx, __shfl_xor(mx, off, 8));

  float e[4];
  #pragma unroll
  for (int i = 0; i < 4; ++i) e[i] = exp_cr(__fsub_rn(lg[i], mx));
  float ssum = e[0];
  ssum = __fadd_rn(ssum, e[1]);
  ssum = __fadd_rn(ssum, e[2]);
  ssum = __fadd_rn(ssum, e[3]);
  ssum = __fadd_rn(ssum, __shfl_xor(ssum, 1, 8));
  ssum = __fadd_rn(ssum, __shfl_xor(ssum, 2, 8));
  ssum = __fadd_rn(ssum, __shfl_xor(ssum, 4, 8));

  float p[4];
  #pragma unroll
  for (int i = 0; i < 4; ++i) {
    float pr = __fdiv_rn(e[i], ssum);
    p[i] = __fadd_rn(__fmul_rn(C0, pr), C1);
  }

  size_t ob = ((size_t)b * 64 + t) * 1024;
  float bv = -3.4e38f; int bc = 33;
  #pragma unroll
  for (int i = 0; i < 4; ++i) {
    int c = lane + 8 * i, col = d * 32 + c;
    out[3 * NOUT + ob + col] = p[i];
    float uu = u_post[((size_t)t * 256 + b) * 1024 + col];
    float l1 = log_cr(uu);
    float v1 = -l1;
    float l2 = log_cr(v1);
    float gu = -l2;
    float lp = log_cr(p[i]);
    float val = __fadd_rn(lp, gu);
    if (val > bv) { bv = val; bc = c; }       // first max (c ascending)
  }
  for (int off = 4; off; off >>= 1) {
    float ov = __shfl_xor(bv, off, 8);
    int   oc = __shfl_xor(bc, off, 8);
    if (ov > bv || (ov == bv && oc < bc)) { bv = ov; bc = oc; }
  }
  #pragma unroll
  for (int i = 0; i < 4; ++i) {
    int c = lane + 8 * i, col = d * 32 + c;
    float zv = 0.0f;
    if (c == bc) zv = __fsub_rn(__fadd_rn(1.0f, p[i]), p[i]);
    out[NOUT + ob + col] = zv;
    XZ[(size_t)b * 1040 + col] = zv;
  }
  if (tid < 6 && (t + 1) < 64)
    XZ[(size_t)b * 1040 + 1024 + tid] = actions[((size_t)b * 64 + (t + 1)) * 6 + tid];
}

// ---- prior softmax+unimix (batched, value-safe: no argmax) -> pp ----
__global__ __launch_bounds__(256) void prior_soft_k(
  const float* Y2c, const float* bp2, float* out, int rows0)
{
  const size_t NOUT = 16777216ull;
  int r = rows0 + blockIdx.x, tid = threadIdx.x;
  int d = tid >> 3, lane = tid & 7;
  const float C0 = (float)(1.0 - 0.01);
  const float C1 = (float)(0.01 / 32.0);

  float lg[4];
  #pragma unroll
  for (int i = 0; i < 4; ++i) {
    int col = d * 32 + lane + 8 * i;
    lg[i] = __fadd_rn(Y2c[(size_t)blockIdx.x * 1024 + col], bp2[col]);
  }
  float mx = fmaxf(fmaxf(lg[0], lg[1]), fmaxf(lg[2], lg[3]));
  for (int off = 4; off; off >>= 1) mx = fmaxf(mx, __shfl_xor(mx, off, 8));
  float e[4];
  #pragma unroll
  for (int i = 0; i < 4; ++i) e[i] = exp_cr(__fsub_rn(lg[i], mx));
  float ssum = e[0];
  ssum = __fadd_rn(ssum, e[1]);
  ssum = __fadd_rn(ssum, e[2]);
  ssum = __fadd_rn(ssum, e[3]);
  ssum = __fadd_rn(ssum, __shfl_xor(ssum, 1, 8));
  ssum = __fadd_rn(ssum, __shfl_xor(ssum, 2, 8));
  ssum = __fadd_rn(ssum, __shfl_xor(ssum, 4, 8));
  #pragma unroll
  for (int i = 0; i < 4; ++i) {
    int col = d * 32 + lane + 8 * i;
    float pr = __fdiv_rn(e[i], ssum);
    out[2 * NOUT + (size_t)r * 1024 + col] = __fadd_rn(__fmul_rn(C0, pr), C1);
  }
}

__global__ __launch_bounds__(256) void init_k(const float* h_init, const float* z_init,
                                              const float* actions, float* H, float* XZ)
{
  int b = blockIdx.x, tid = threadIdx.x;
  #pragma unroll
  for (int j = 0; j < 4; ++j) {
    int n = tid + j * 256;
    H [(size_t)b * 1024 + n] = h_init[(size_t)b * 1024 + n];
    XZ[(size_t)b * 1040 + n] = z_init[(size_t)b * 1024 + n];
  }
  if (tid < 6) XZ[(size_t)b * 1040 + 1024 + tid] = actions[(size_t)b * 64 * 6 + tid];
}

extern "C" void kernel_launch(void* const* d_in, const int* in_sizes, int n_in,
                              void* d_out, int out_size, void* d_ws, size_t ws_size,
                              hipStream_t stream)
{
  const float* embeds  = (const float*)d_in[0];
  const float* actions = (const float*)d_in[1];
  const float* h_init  = (const float*)d_in[2];
  const float* z_init  = (const float*)d_in[3];
  const float* W_pre   = (const float*)d_in[4];
  const float* b_pre   = (const float*)d_in[5];
  const float* g_pre   = (const float*)d_in[6];
  const float* be_pre  = (const float*)d_in[7];
  const float* W_ih    = (const float*)d_in[8];
  const float* W_hh    = (const float*)d_in[9];
  const float* b_ih    = (const float*)d_in[10];
  const float* b_hh    = (const float*)d_in[11];
  const float* g_gn    = (const float*)d_in[12];
  const float* b_gn    = (const float*)d_in[13];
  const float* Wp1     = (const float*)d_in[14];
  const float* bp1     = (const float*)d_in[15];
  const float* gp      = (const float*)d_in[16];
  const float* bpn     = (const float*)d_in[17];
  const float* Wp2     = (const float*)d_in[18];
  const float* bp2     = (const float*)d_in[19];
  const float* Wq1     = (const float*)d_in[20];
  const float* bq1     = (const float*)d_in[21];
  const float* gq      = (const float*)d_in[22];
  const float* bqn     = (const float*)d_in[23];
  const float* Wq2     = (const float*)d_in[24];
  const float* bq2     = (const float*)d_in[25];
  // d_in[26] = u_prior: unused
  const float* u_post  = (const float*)d_in[27];
  float* out           = (float*)d_out;

  // f32 workspace, 6,295,552 floats = 25.2 MB (same footprint as r7)
  float* W0   = (float*)d_ws;
  float* H    = W0;                       // 262144
  float* XZ   = W0 + 262144;              // 266240 (row stride 1040)
  float* XPRE = W0 + 528384;              // 262144
  float* PREY = W0 + 790528;              // 786432 (3 panels)
  float* A0   = W0 + 1576960;             // region A: 4718592
  float* GX   = A0;                       // 2359296 (3 panels)   [steps 3-4]
  float* GH   = A0 + 2359296;             // 2359296              [steps 3-4]
  float* YQ   = A0;                       // 1572864 (6 panels)   [steps 5-6]
  float* YQ2  = A0 + 1572864;             // 786432 (3 panels)    [steps 7-8]
  float* Q1A  = A0 + 2359296;             // 262144               [steps 6-7]
  float* Y1c  = A0;                       // 2097152 (post-loop prior chunk)
  float* Y2c  = A0 + 2097152;             // 2097152 (post-loop prior chunk)

  hipLaunchKernelGGL(init_k, dim3(256), dim3(256), 0, stream, h_init, z_init, actions, H, XZ);

  for (int t = 0; t < 64; ++t) {
    // 1) PREY[s] = panel_s([z|a] @ W_pre^T)   K=1030, 3 panels
    GArg pre{XZ, 1040, XZ, 1040, 1030, W_pre, 1030, PREY, 1024, 1030};
    hipLaunchKernelGGL(gemm_k, dim3(16, 4, 3), dim3(256), 0, stream, pre, pre, 3, 24);
    // 2) XPRE = silu(LN(fold3(PREY) + b_pre))
    hipLaunchKernelGGL(lnsilu_k, dim3(256), dim3(64), 0, stream,
                       PREY, 3, b_pre, g_pre, be_pre, XPRE);
    // 3) GX[s] = panel_s(XPRE @ W_ih^T); GH[s] = panel_s(H @ W_hh^T)  N=3072
    GArg gx{XPRE, 1024, XPRE, 1024, 1024, W_ih, 1024, GX, 3072, 1024};
    GArg gh{H,    1024, H,    1024, 1024, W_hh, 1024, GH, 3072, 1024};
    hipLaunchKernelGGL(gemm_k, dim3(48, 4, 6), dim3(256), 0, stream, gx, gh, 3, 24);
    // 4) GRU combine (fold3) + LN -> H, hs
    hipLaunchKernelGGL(gru_k, dim3(256), dim3(64), 0, stream,
                       GX, GH, H, b_ih, b_hh, g_gn, b_gn, out, t);
    // 5) YQ[s] = panel_s([H|e_t] @ Wq1^T)  K=2048, 6 panels
    GArg q1{H, 1024, embeds + (size_t)t * 1024, 65536, 1024, Wq1, 2048, YQ, 1024, 2048};
    hipLaunchKernelGGL(gemm_k, dim3(16, 4, 6), dim3(256), 0, stream, q1, q1, 6, 24);
    // 6) Q1A = silu(LN(fold6(YQ)+bq1))
    hipLaunchKernelGGL(lnsilu_k, dim3(256), dim3(64), 0, stream,
                       YQ, 6, bq1, gq, bqn, Q1A);
    // 7) YQ2[s] = panel_s(Q1A @ Wq2^T)  3 panels
    GArg q2{Q1A, 1024, Q1A, 1024, 1024, Wq2, 1024, YQ2, 1024, 1024};
    hipLaunchKernelGGL(gemm_k, dim3(16, 4, 3), dim3(256), 0, stream, q2, q2, 3, 24);
    // 8) posterior softmax+unimix+gumbel argmax -> qp/zs, next [z|a]
    hipLaunchKernelGGL(sample_post_k, dim3(256), dim3(256), 0, stream,
                       YQ2, bq2, u_post, actions, XZ, out, t);
  }

  // ---- batched prior chain over hs (value-safe), 8 chunks of 2048 rows ----
  for (int bc = 0; bc < 8; ++bc) {
    const float* hsrc = out + (size_t)bc * 2048 * 1024;   // hs rows b-major
    GArg y1{hsrc, 1024, hsrc, 1024, 1 << 30, Wp1, 1024, Y1c, 1024, 1024};
    hipLaunchKernelGGL(gemm_k, dim3(16, 32, 1), dim3(256), 0, stream, y1, y1, 1, 64);
    hipLaunchKernelGGL(lnsilu_k, dim3(2048), dim3(64), 0, stream,
                       Y1c, 1, bp1, gp, bpn, Y1c);        // in-place (wave-local)
    GArg y2{Y1c, 1024, Y1c, 1024, 1 << 30, Wp2, 1024, Y2c, 1024, 1024};
    hipLaunchKernelGGL(gemm_k, dim3(16, 32, 1), dim3(256), 0, stream, y2, y2, 1, 64);
    hipLaunchKernelGGL(prior_soft_k, dim3(2048), dim3(256), 0, stream,
                       Y2c, bp2, out, bc * 2048);
  }
}